// Round 1
// baseline (128.089 us; speedup 1.0000x reference)
//
#include <hip/hip_runtime.h>

// Problem: CompositionTransform  B=2, C=3, D=128, H=160, W=160, range_flow=0.4
// out[b,c,d,h,w] = trilerp_border(flow_2[b,c], clamp((w,h,d) + rf*flow_1[b,:,d,h,w])) + flow_1[b,c,d,h,w]
// sample_grid is the identity meshgrid -> computed from indices, never read.

constexpr int BB = 2;
constexpr int DD = 128;
constexpr int HH = 160;
constexpr int WW = 160;
constexpr int SP = DD * HH * WW;            // 3,276,800 spatial elems per batch
constexpr long TOT = (long)BB * SP;         // 6,553,600 threads, exact multiple of 256

__global__ __launch_bounds__(256) void comp_xform_kernel(
    const float* __restrict__ f1,
    const float* __restrict__ f2,
    const float* __restrict__ rfp,
    float* __restrict__ out)
{
    const int i = blockIdx.x * 256 + threadIdx.x;   // grid sized exactly
    const float rf = rfp[0];

    // decode (b,d,h,w); compiler emits magic-multiply for const divides
    int w = i % WW;
    int t = i / WW;
    int h = t % HH;
    t = t / HH;
    int d = t % DD;
    int b = t / DD;

    const size_t boff = (size_t)b * (size_t)(3 * SP);
    const int sp = (d * HH + h) * WW + w;

    const float* f1b = f1 + boff;
    const float f1x = f1b[sp];
    const float f1y = f1b[SP + sp];
    const float f1z = f1b[2 * SP + sp];

    // sample position, border-clamped (normalize/denormalize cancels)
    float x = fminf(fmaxf((float)w + rf * f1x, 0.0f), (float)(WW - 1));
    float y = fminf(fmaxf((float)h + rf * f1y, 0.0f), (float)(HH - 1));
    float z = fminf(fmaxf((float)d + rf * f1z, 0.0f), (float)(DD - 1));

    float x0f = floorf(x), y0f = floorf(y), z0f = floorf(z);
    float wx = x - x0f, wy = y - y0f, wz = z - z0f;
    int ix0 = (int)x0f, iy0 = (int)y0f, iz0 = (int)z0f;
    int ix1 = min(ix0 + 1, WW - 1);
    int iy1 = min(iy0 + 1, HH - 1);
    int iz1 = min(iz0 + 1, DD - 1);

    const int b00 = (iz0 * HH + iy0) * WW;
    const int b01 = (iz0 * HH + iy1) * WW;
    const int b10 = (iz1 * HH + iy0) * WW;
    const int b11 = (iz1 * HH + iy1) * WW;

    const float* f2b = f2 + boff;
    float* ob = out + boff + sp;
    const float f1c[3] = { f1x, f1y, f1z };

#pragma unroll
    for (int c = 0; c < 3; ++c) {
        const float* v = f2b + (size_t)c * SP;
        float c000 = v[b00 + ix0], c001 = v[b00 + ix1];
        float c010 = v[b01 + ix0], c011 = v[b01 + ix1];
        float c100 = v[b10 + ix0], c101 = v[b10 + ix1];
        float c110 = v[b11 + ix0], c111 = v[b11 + ix1];

        float c00 = c000 * (1.0f - wx) + c001 * wx;
        float c01 = c010 * (1.0f - wx) + c011 * wx;
        float c10 = c100 * (1.0f - wx) + c101 * wx;
        float c11 = c110 * (1.0f - wx) + c111 * wx;
        float c0  = c00  * (1.0f - wy) + c01  * wy;
        float c1  = c10  * (1.0f - wy) + c11  * wy;
        float r   = c0   * (1.0f - wz) + c1   * wz;

        ob[(size_t)c * SP] = r + f1c[c];
    }
}

extern "C" void kernel_launch(void* const* d_in, const int* in_sizes, int n_in,
                              void* d_out, int out_size, void* d_ws, size_t ws_size,
                              hipStream_t stream) {
    const float* f1  = (const float*)d_in[0];
    const float* f2  = (const float*)d_in[1];
    // d_in[2] = sample_grid (identity meshgrid) — unused by construction
    const float* rfp = (const float*)d_in[3];
    float* out = (float*)d_out;

    const int threads = 256;
    const int blocks = (int)(TOT / threads);   // 25600, exact
    comp_xform_kernel<<<blocks, threads, 0, stream>>>(f1, f2, rfp, out);
}

// Round 2
// 125.339 us; speedup vs baseline: 1.0219x; 1.0219x over previous
//
#include <hip/hip_runtime.h>

// CompositionTransform  B=2, C=3, D=128, H=160, W=160, range_flow=0.4
// out[b,c,d,h,w] = trilerp_border(flow_2[b,c], (w,h,d) + rf*flow_1[b,:,d,h,w]) + flow_1[b,c,d,h,w]
// sample_grid is the identity meshgrid -> computed from indices, never read.
//
// R1: issue-all-loads-first (batch 27 VMEM ops in flight), block-uniform batch/base
//     (SGPR bases + 32-bit offsets), XCD-chunked block swizzle for z-plane L2 reuse,
//     shared trilinear weights across channels.

constexpr int DD = 128;
constexpr int HH = 160;
constexpr int WW = 160;
constexpr int SP = DD * HH * WW;           // 3,276,800 (multiple of 256)
constexpr int BLOCKS_PER_B = SP / 256;     // 12,800
constexpr int NB = 2 * BLOCKS_PER_B;       // 25,600 (multiple of 8)

__global__ __launch_bounds__(256) void comp_xform_kernel(
    const float* __restrict__ f1,
    const float* __restrict__ f2,
    const float* __restrict__ rfp,
    float* __restrict__ out)
{
    // XCD-chunked swizzle: XCD k owns a contiguous range of 3200 blocks
    // (= 32 consecutive d-planes of one batch) -> z-plane reuse stays in one L2.
    const int bid = blockIdx.x;
    const int wg  = (bid & 7) * (NB / 8) + (bid >> 3);

    // block-uniform batch index and spatial base (kept scalar by construction)
    const int b   = wg / BLOCKS_PER_B;
    const int spb = (wg - b * BLOCKS_PER_B) * 256;
    const int sp  = spb + threadIdx.x;

    const float rf = rfp[0];

    // decode (d,h,w) from sp
    const int w = sp % WW;
    const int t = sp / WW;
    const int h = t % HH;
    const int d = t / HH;

    const size_t boff = (size_t)b * (size_t)(3 * SP);
    const float* __restrict__ f1b = f1 + boff;
    const float* __restrict__ f2b = f2 + boff;
    float* __restrict__ ob = out + boff;

    // flow_1 at this voxel (3 channels)
    const float f1x = f1b[sp];
    const float f1y = f1b[SP + sp];
    const float f1z = f1b[2 * SP + sp];

    // sample position, border-clamped (reference's normalize/denormalize cancels)
    float x = fminf(fmaxf((float)w + rf * f1x, 0.0f), (float)(WW - 1));
    float y = fminf(fmaxf((float)h + rf * f1y, 0.0f), (float)(HH - 1));
    float z = fminf(fmaxf((float)d + rf * f1z, 0.0f), (float)(DD - 1));

    const float x0f = floorf(x), y0f = floorf(y), z0f = floorf(z);
    const float wx = x - x0f, wy = y - y0f, wz = z - z0f;
    const int ix0 = (int)x0f, iy0 = (int)y0f, iz0 = (int)z0f;
    const int ix1 = min(ix0 + 1, WW - 1);
    const int iy1 = min(iy0 + 1, HH - 1);
    const int iz1 = min(iz0 + 1, DD - 1);

    const int r00 = (iz0 * HH + iy0) * WW;
    const int r01 = (iz0 * HH + iy1) * WW;
    const int r10 = (iz1 * HH + iy0) * WW;
    const int r11 = (iz1 * HH + iy1) * WW;

    const int o0 = r00 + ix0, o1 = r00 + ix1;
    const int o2 = r01 + ix0, o3 = r01 + ix1;
    const int o4 = r10 + ix0, o5 = r10 + ix1;
    const int o6 = r11 + ix0, o7 = r11 + ix1;

    // ---- issue ALL 24 gathers into distinct registers before any use ----
    float v[3][8];
#pragma unroll
    for (int c = 0; c < 3; ++c) {
        const float* __restrict__ p = f2b + c * SP;
        v[c][0] = p[o0]; v[c][1] = p[o1];
        v[c][2] = p[o2]; v[c][3] = p[o3];
        v[c][4] = p[o4]; v[c][5] = p[o5];
        v[c][6] = p[o6]; v[c][7] = p[o7];
    }

    // trilinear weights, shared across the 3 channels
    const float ax = 1.0f - wx, ay = 1.0f - wy, az = 1.0f - wz;
    const float w00 = ax * ay, w01 = wx * ay, w10 = ax * wy, w11 = wx * wy;
    const float k0 = w00 * az, k1 = w01 * az, k2 = w10 * az, k3 = w11 * az;
    const float k4 = w00 * wz, k5 = w01 * wz, k6 = w10 * wz, k7 = w11 * wz;

    const float f1c[3] = { f1x, f1y, f1z };
#pragma unroll
    for (int c = 0; c < 3; ++c) {
        float r = v[c][0] * k0 + v[c][1] * k1
                + v[c][2] * k2 + v[c][3] * k3
                + v[c][4] * k4 + v[c][5] * k5
                + v[c][6] * k6 + v[c][7] * k7;
        ob[(size_t)c * SP + sp] = r + f1c[c];
    }
}

extern "C" void kernel_launch(void* const* d_in, const int* in_sizes, int n_in,
                              void* d_out, int out_size, void* d_ws, size_t ws_size,
                              hipStream_t stream) {
    const float* f1  = (const float*)d_in[0];
    const float* f2  = (const float*)d_in[1];
    // d_in[2] = sample_grid (identity meshgrid) — unused by construction
    const float* rfp = (const float*)d_in[3];
    float* out = (float*)d_out;

    comp_xform_kernel<<<NB, 256, 0, stream>>>(f1, f2, rfp, out);
}

// Round 3
// 90.680 us; speedup vs baseline: 1.4125x; 1.3822x over previous
//
#include <hip/hip_runtime.h>

// CompositionTransform  B=2, C=3, D=128, H=160, W=160, range_flow=0.4
// out[b,c,d,h,w] = trilerp_border(flow_2[b,c], (w,h,d) + rf*flow_1[b,:,d,h,w]) + flow_1[b,c,d,h,w]
// sample_grid is the identity meshgrid -> computed from indices, never read.
//
// R2: pair the x0/x1 gathers into dwordx2 loads (24 -> 12 gather instrs/thread).
//     Pairs are adjacent in x -> same 128B line ~97% of the time, halving the
//     TA line-request traffic that R1 showed to be the bottleneck (dur was
//     insensitive to FETCH_SIZE halving; VALU 18%, HBM 13% -> VMEM-issue bound).
//     Border: load pair from xb=min(ix0,W-2), cndmask the low element when
//     ix0==W-1 (there wx==0 so the high element's weight is zero).

constexpr int DD = 128;
constexpr int HH = 160;
constexpr int WW = 160;
constexpr int SP = DD * HH * WW;           // 3,276,800 (multiple of 256)
constexpr int BLOCKS_PER_B = SP / 256;     // 12,800
constexpr int NB = 2 * BLOCKS_PER_B;       // 25,600 (multiple of 8)

__global__ __launch_bounds__(256) void comp_xform_kernel(
    const float* __restrict__ f1,
    const float* __restrict__ f2,
    const float* __restrict__ rfp,
    float* __restrict__ out)
{
    // XCD-chunked swizzle: keeps z-plane reuse within one XCD's L2.
    const int bid = blockIdx.x;
    const int wg  = (bid & 7) * (NB / 8) + (bid >> 3);

    const int b   = wg / BLOCKS_PER_B;
    const int spb = (wg - b * BLOCKS_PER_B) * 256;
    const int sp  = spb + threadIdx.x;

    const float rf = rfp[0];

    const int w = sp % WW;
    const int t = sp / WW;
    const int h = t % HH;
    const int d = t / HH;

    const size_t boff = (size_t)b * (size_t)(3 * SP);
    const float* __restrict__ f1b = f1 + boff;
    const float* __restrict__ f2b = f2 + boff;
    float* __restrict__ ob = out + boff;

    const float f1x = f1b[sp];
    const float f1y = f1b[SP + sp];
    const float f1z = f1b[2 * SP + sp];

    float x = fminf(fmaxf((float)w + rf * f1x, 0.0f), (float)(WW - 1));
    float y = fminf(fmaxf((float)h + rf * f1y, 0.0f), (float)(HH - 1));
    float z = fminf(fmaxf((float)d + rf * f1z, 0.0f), (float)(DD - 1));

    const float x0f = floorf(x), y0f = floorf(y), z0f = floorf(z);
    const float wx = x - x0f, wy = y - y0f, wz = z - z0f;
    const int ix0 = (int)x0f, iy0 = (int)y0f, iz0 = (int)z0f;
    const int iy1 = min(iy0 + 1, HH - 1);
    const int iz1 = min(iz0 + 1, DD - 1);

    // x-pair base: never OOB; when ix0==W-1 the valid value sits in .y and wx==0.
    const int  xb = min(ix0, WW - 2);
    const bool hi = (ix0 > xb);

    const int o00 = (iz0 * HH + iy0) * WW + xb;
    const int o01 = (iz0 * HH + iy1) * WW + xb;
    const int o10 = (iz1 * HH + iy0) * WW + xb;
    const int o11 = (iz1 * HH + iy1) * WW + xb;

    // ---- issue all 12 paired gathers before any consumption ----
    float2 q[3][4];
#pragma unroll
    for (int c = 0; c < 3; ++c) {
        const float* __restrict__ p = f2b + c * SP;
        q[c][0] = *reinterpret_cast<const float2*>(p + o00);
        q[c][1] = *reinterpret_cast<const float2*>(p + o01);
        q[c][2] = *reinterpret_cast<const float2*>(p + o10);
        q[c][3] = *reinterpret_cast<const float2*>(p + o11);
    }

    // trilinear weights shared across channels; per-pair (even=lo=x0, odd=hi=x1)
    const float ax = 1.0f - wx, ay = 1.0f - wy, az = 1.0f - wz;
    const float w00 = ay * az, w01 = wy * az, w10 = ay * wz, w11 = wy * wz;
    const float ke[4] = { ax * w00, ax * w01, ax * w10, ax * w11 };
    const float ko[4] = { wx * w00, wx * w01, wx * w10, wx * w11 };

    const float f1c[3] = { f1x, f1y, f1z };
#pragma unroll
    for (int c = 0; c < 3; ++c) {
        float r = 0.0f;
#pragma unroll
        for (int k = 0; k < 4; ++k) {
            const float lo = hi ? q[c][k].y : q[c][k].x;   // border select
            r = fmaf(lo, ke[k], fmaf(q[c][k].y, ko[k], r));
        }
        ob[(size_t)c * SP + sp] = r + f1c[c];
    }
}

extern "C" void kernel_launch(void* const* d_in, const int* in_sizes, int n_in,
                              void* d_out, int out_size, void* d_ws, size_t ws_size,
                              hipStream_t stream) {
    const float* f1  = (const float*)d_in[0];
    const float* f2  = (const float*)d_in[1];
    // d_in[2] = sample_grid (identity meshgrid) — unused by construction
    const float* rfp = (const float*)d_in[3];
    float* out = (float*)d_out;

    comp_xform_kernel<<<NB, 256, 0, stream>>>(f1, f2, rfp, out);
}